// Round 1
// baseline (1509.475 us; speedup 1.0000x reference)
//
#include <hip/hip_runtime.h>
#include <math.h>

typedef float fx4 __attribute__((ext_vector_type(4)));
typedef _Float16 hx8 __attribute__((ext_vector_type(8)));

// ---------------------------------------------------------------- embed gather
__global__ __launch_bounds__(256)
void embed_k(const int* __restrict__ ids, const float* __restrict__ emb,
             float* __restrict__ x)
{
  int t = blockIdx.x;
  int id = ids[t];
  fx4 v = *(const fx4*)(emb + (size_t)id * 1024 + threadIdx.x * 4);
  *(fx4*)(x + (size_t)t * 1024 + threadIdx.x * 4) = v;
}

// ---------------------------------------------------------------- generic GEMM
// C[M,N] = A[M,K] @ B[N,K]^T (+bias[N]); fp32 in/out, f16 MFMA, fp32 accum.
// 128x128 tile, BK=64, 4 waves, double-buffered LDS, reg-staged conversion.
__global__ __launch_bounds__(256, 2)
void gemm_bt(const float* __restrict__ A, const float* __restrict__ B,
             float* __restrict__ C, const float* __restrict__ bias,
             int M, int N, int K)
{
  __shared__ hx8 lA[2][1024];
  __shared__ hx8 lB[2][1024];
  const int tid = threadIdx.x;
  const int m0 = blockIdx.x << 7, n0 = blockIdx.y << 7;
  const int row = tid & 127, kh = tid >> 7;
  int brI = n0 + row; if (brI > N - 1) brI = N - 1;   // clamp (garbage masked at store)
  const float* pa = A + (size_t)(m0 + row) * K + (kh << 5);
  const float* pb = B + (size_t)brI * K + (kh << 5);
  const int lane = tid & 63, w = tid >> 6, wr = w >> 1, wc = w & 1;
  const int lm = lane & 15, lg = lane >> 4;
  const int nk = K >> 6;

  fx4 ra[8], rb[8];
  #pragma unroll
  for (int q = 0; q < 8; q++){
    ra[q] = *(const fx4*)(pa + q * 4);
    rb[q] = *(const fx4*)(pb + q * 4);
  }
  fx4 acc[4][4];
  #pragma unroll
  for (int mt = 0; mt < 4; mt++)
    #pragma unroll
    for (int nt = 0; nt < 4; nt++)
      acc[mt][nt] = (fx4){0.f, 0.f, 0.f, 0.f};

  #pragma unroll
  for (int o = 0; o < 4; o++){
    hx8 ha, hb;
    #pragma unroll
    for (int e = 0; e < 4; e++){
      ha[e] = (_Float16)ra[o*2][e];  ha[4+e] = (_Float16)ra[o*2+1][e];
      hb[e] = (_Float16)rb[o*2][e];  hb[4+e] = (_Float16)rb[o*2+1][e];
    }
    lA[0][(kh*4 + o)*128 + row] = ha;
    lB[0][(kh*4 + o)*128 + row] = hb;
  }
  __syncthreads();

  int buf = 0;
  for (int kt = 0; kt < nk; kt++){
    if (kt + 1 < nk){
      const float* qa = pa + (kt + 1) * 64;
      const float* qb = pb + (kt + 1) * 64;
      #pragma unroll
      for (int q = 0; q < 8; q++){
        ra[q] = *(const fx4*)(qa + q * 4);
        rb[q] = *(const fx4*)(qb + q * 4);
      }
    }
    #pragma unroll
    for (int s = 0; s < 2; s++){
      hx8 af[4], bfr[4];
      #pragma unroll
      for (int mt = 0; mt < 4; mt++)
        af[mt] = lA[buf][(s*4 + lg)*128 + wr*64 + mt*16 + lm];
      #pragma unroll
      for (int nt = 0; nt < 4; nt++)
        bfr[nt] = lB[buf][(s*4 + lg)*128 + wc*64 + nt*16 + lm];
      #pragma unroll
      for (int mt = 0; mt < 4; mt++)
        #pragma unroll
        for (int nt = 0; nt < 4; nt++)
          acc[mt][nt] = __builtin_amdgcn_mfma_f32_16x16x32_f16(af[mt], bfr[nt], acc[mt][nt], 0, 0, 0);
    }
    if (kt + 1 < nk){
      buf ^= 1;
      #pragma unroll
      for (int o = 0; o < 4; o++){
        hx8 ha, hb;
        #pragma unroll
        for (int e = 0; e < 4; e++){
          ha[e] = (_Float16)ra[o*2][e];  ha[4+e] = (_Float16)ra[o*2+1][e];
          hb[e] = (_Float16)rb[o*2][e];  hb[4+e] = (_Float16)rb[o*2+1][e];
        }
        lA[buf][(kh*4 + o)*128 + row] = ha;
        lB[buf][(kh*4 + o)*128 + row] = hb;
      }
    }
    __syncthreads();
  }

  #pragma unroll
  for (int nt = 0; nt < 4; nt++){
    int col = n0 + wc*64 + nt*16 + lm;
    if (col < N){
      float bs = bias ? bias[col] : 0.f;
      #pragma unroll
      for (int mt = 0; mt < 4; mt++){
        int r0 = m0 + wr*64 + mt*16 + (lg << 2);
        #pragma unroll
        for (int j = 0; j < 4; j++)
          C[(size_t)(r0 + j) * N + col] = acc[mt][nt][j] + bs;
      }
    }
  }
}

// ---------------------------------------------------------------- gk / beta
__global__ __launch_bounds__(64)
void gkbeta_k(const float* __restrict__ x, const float* __restrict__ Wgk,
              const float* __restrict__ Wb, const float* __restrict__ b_b,
              const float* __restrict__ A_log, const float* __restrict__ dtb,
              float* __restrict__ gko, float* __restrict__ beto)
{
  int t = blockIdx.x, h = blockIdx.y, lane = threadIdx.x;
  const float* xr = x + (size_t)t * 1024;
  float a = 0.f, b = 0.f;
  #pragma unroll
  for (int j = 0; j < 16; j++){
    int idx = lane + j * 64;
    float xv = xr[idx];
    a += xv * Wgk[h * 1024 + idx];
    b += xv * Wb [h * 1024 + idx];
  }
  #pragma unroll
  for (int d = 1; d < 64; d <<= 1){
    a += __shfl_xor(a, d, 64);
    b += __shfl_xor(b, d, 64);
  }
  if (lane == 0){
    float z = a + dtb[h];
    float sp = (z > 20.f) ? z : log1pf(expf(z));
    gko [(size_t)t * 12 + h] = -expf(A_log[h]) * sp;
    beto[(size_t)t * 12 + h] = 1.f / (1.f + expf(-(b + b_b[h])));
  }
}

// ---------------------------------------------------------------- conv + silu (+l2norm)
__global__ __launch_bounds__(64)
void conv_silu(const float* __restrict__ in, const float* __restrict__ cw,
               float* __restrict__ outp, int D, int donorm, float scale)
{
  int t = blockIdx.x, hg = blockIdx.y, lane = threadIdx.x;
  int ch = hg * 64 + lane;
  float y = 0.f;
  #pragma unroll
  for (int i = 0; i < 4; i++){
    int ts = t - 3 + i;
    if (ts >= 0) y += cw[ch * 4 + i] * in[(size_t)ts * D + ch];
  }
  y = y / (1.f + expf(-y));                 // silu
  if (donorm){
    float ss = y * y;
    #pragma unroll
    for (int d = 1; d < 64; d <<= 1) ss += __shfl_xor(ss, d, 64);
    y *= rsqrtf(ss + 1e-6f) * scale;        // l2norm over head (+q scale)
  }
  outp[(size_t)t * D + ch] = y;
}

// ---------------------------------------------------------------- phase A: per-(head,chunk) WY factors
__global__ __launch_bounds__(256)
void phaseA(const float* __restrict__ qp, const float* __restrict__ kp,
            const float* __restrict__ vp, const float* __restrict__ gkv,
            const float* __restrict__ bev, float* __restrict__ Wt,
            float* __restrict__ Uvv, float* __restrict__ Mg,
            float* __restrict__ Ng, float* __restrict__ Ca,
            float* __restrict__ bv)
{
  const int blk = blockIdx.x;
  const int h = blk % 12, c = blk / 12, t0 = c * 64;
  const int tid = threadIdx.x;

  __shared__ __align__(16) float Kc[4096];     // K chunk [64][64]
  __shared__ __align__(16) float X[12288];     // [64][192]: cols 0..127 Uv, 128..191 W
  __shared__ float Pp[2016];                   // packed strict-lower P
  __shared__ float gt[64], bb[64], be[64], eg[64];
  __shared__ float Gtot;

  { // load K chunk
    int i = tid >> 2, q4 = tid & 3;
    const float* src = kp + (size_t)(t0 + i) * 768 + h * 64 + q4 * 16;
    #pragma unroll
    for (int e = 0; e < 4; e++)
      *(fx4*)&Kc[i * 64 + q4 * 16 + e * 4] = *(const fx4*)(src + e * 4);
  }
  if (tid < 64){ // within-chunk cumulative log-decay
    float g = gkv[(size_t)(t0 + tid) * 12 + h];
    #pragma unroll
    for (int d = 1; d < 64; d <<= 1){
      float ts = __shfl_up(g, d, 64);
      if (tid >= d) g += ts;
    }
    gt[tid] = g;
    bb[tid] = expf(g);
    be[tid] = bev[(size_t)(t0 + tid) * 12 + h];
    if (tid == 63) Gtot = g;
  }
  __syncthreads();
  const float GT = Gtot;
  if (tid < 64) eg[tid] = expf(GT - gt[tid]);

  { // P_ij = beta_i * (k_i.k_j) * exp(gt_i - gt_j), j < i
    int i = tid >> 2, jb = tid & 3;
    float ki[64];
    #pragma unroll
    for (int d = 0; d < 64; d++) ki[d] = Kc[i * 64 + d];
    float gi = gt[i], bei = be[i];
    int pbase = (i * (i - 1)) >> 1;
    for (int jj = 0; jj < 16; jj++){
      int j = jb * 16 + jj;
      if (j < i){
        float dot = 0.f;
        #pragma unroll
        for (int d = 0; d < 64; d++) dot += ki[d] * Kc[j * 64 + d];
        Pp[pbase + j] = bei * dot * expf(gi - gt[j]);
      }
    }
  }
  { // X init = diag(beta)[V | diag(b)K]
    int i = tid >> 2, seg = tid & 3;
    float bei = be[i], bbi = bb[i];
    #pragma unroll
    for (int u = 0; u < 12; u++){
      int colv = seg * 48 + u * 4;
      fx4 val;
      if (colv < 128){
        val = *(const fx4*)(vp + (size_t)(t0 + i) * 1536 + h * 128 + colv);
        #pragma unroll
        for (int e = 0; e < 4; e++) val[e] *= bei;
      } else {
        int d0 = colv - 128;
        #pragma unroll
        for (int e = 0; e < 4; e++) val[e] = bei * bbi * Kc[i * 64 + d0 + e];
      }
      *(fx4*)&X[i * 192 + colv] = val;
    }
  }
  __syncthreads();

  // forward substitution: X <- (I+P)^-1 X
  for (int i = 1; i < 64; i++){
    if (tid < 192){
      int pbase = (i * (i - 1)) >> 1;
      float accv = 0.f;
      for (int j = 0; j < i; j++) accv += Pp[pbase + j] * X[j * 192 + tid];
      X[i * 192 + tid] -= accv;
    }
    __syncthreads();
  }

  // store Uv, W
  for (int e = tid; e < 12288; e += 256){
    int i = e / 192, colv = e - i * 192;
    float xv = X[e];
    if (colv < 128) Uvv[(size_t)blk * 8192 + i * 128 + colv] = xv;
    else            Wt [(size_t)blk * 4096 + i * 64 + (colv - 128)] = xv;
  }

  { // M = exp(G) I - K'^T W
    int d2 = tid & 63, d1b = tid >> 6;
    for (int ii = 0; ii < 16; ii++){
      int d1 = d1b * 16 + ii;
      float s = 0.f;
      for (int j = 0; j < 64; j++)
        s += eg[j] * Kc[j * 64 + d1] * X[j * 192 + 128 + d2];
      Mg[(size_t)blk * 4096 + d1 * 64 + d2] = ((d1 == d2) ? expf(GT) : 0.f) - s;
    }
  }
  { // N = K'^T Uv
    int vv = tid & 127, d1b = tid >> 7;
    for (int ii = 0; ii < 32; ii++){
      int d1 = d1b * 32 + ii;
      float s = 0.f;
      for (int j = 0; j < 64; j++)
        s += eg[j] * Kc[j * 64 + d1] * X[j * 192 + vv];
      Ng[(size_t)blk * 8192 + d1 * 128 + vv] = s;
    }
  }
  { // Cattn_ij = (q_i.k_j) exp(gt_i-gt_j), j <= i
    int i = tid >> 2, jb = tid & 3;
    float qi[64];
    {
      const float* src = qp + (size_t)(t0 + i) * 768 + h * 64;
      #pragma unroll
      for (int q4 = 0; q4 < 16; q4++){
        fx4 t4 = *(const fx4*)(src + q4 * 4);
        #pragma unroll
        for (int e = 0; e < 4; e++) qi[q4 * 4 + e] = t4[e];
      }
    }
    float gi = gt[i];
    for (int jj = 0; jj < 16; jj++){
      int j = jb * 16 + jj;
      float outv = 0.f;
      if (j <= i){
        float dot = 0.f;
        #pragma unroll
        for (int d = 0; d < 64; d++) dot += qi[d] * Kc[j * 64 + d];
        outv = dot * expf(gi - gt[j]);
      }
      Ca[(size_t)blk * 4096 + i * 64 + j] = outv;
    }
  }
  if (tid < 64) bv[(size_t)blk * 64 + tid] = bb[tid];
}

// ---------------------------------------------------------------- phase B: sequential S <- M S + N (per head)
__global__ __launch_bounds__(256)
void phaseB(const float* __restrict__ Mg, const float* __restrict__ Ng,
            float* __restrict__ Sst)
{
  const int h = blockIdx.x;
  const int tid = threadIdx.x, lane = tid & 63, w = tid >> 6;
  const int lm = lane & 15, lg = lane >> 4;
  __shared__ __align__(16) float ST[8192];   // S in [k-octet][v][8] layout

  #pragma unroll
  for (int e = 0; e < 8; e++)
    *(fx4*)&ST[(tid + e * 256) * 4] = (fx4){0.f,0.f,0.f,0.f};
  {
    float* dst = Sst + (size_t)h * 8192;     // S_states[0] = 0
    #pragma unroll
    for (int e = 0; e < 8; e++)
      *(fx4*)(dst + (size_t)(tid + e * 256) * 4) = (fx4){0.f,0.f,0.f,0.f};
  }
  __syncthreads();

  fx4 rm[2][2];
  float rn[8][4];
  auto loadMN = [&](int cc){
    const float* mb = Mg + ((size_t)cc * 12 + h) * 4096 + (w * 16 + lm) * 64 + lg * 8;
    rm[0][0] = *(const fx4*)(mb);
    rm[0][1] = *(const fx4*)(mb + 4);
    rm[1][0] = *(const fx4*)(mb + 32);
    rm[1][1] = *(const fx4*)(mb + 36);
    const float* nb = Ng + ((size_t)cc * 12 + h) * 8192;
    #pragma unroll
    for (int nt = 0; nt < 8; nt++)
      #pragma unroll
      for (int j = 0; j < 4; j++)
        rn[nt][j] = nb[(w * 16 + lg * 4 + j) * 128 + nt * 16 + lm];
  };
  loadMN(0);

  for (int c = 0; c < 32; c++){
    hx8 mf[2];
    #pragma unroll
    for (int s = 0; s < 2; s++)
      #pragma unroll
      for (int e = 0; e < 4; e++){
        mf[s][e]     = (_Float16)rm[s][0][e];
        mf[s][4 + e] = (_Float16)rm[s][1][e];
      }
    fx4 acc[8];
    #pragma unroll
    for (int nt = 0; nt < 8; nt++)
      #pragma unroll
      for (int j = 0; j < 4; j++) acc[nt][j] = rn[nt][j];
    if (c + 1 < 32) loadMN(c + 1);

    hx8 bfr[2][8];
    #pragma unroll
    for (int s = 0; s < 2; s++)
      #pragma unroll
      for (int nt = 0; nt < 8; nt++){
        int vv = nt * 16 + lm, kb = s * 4 + lg;
        fx4 p0 = *(const fx4*)&ST[kb * 1024 + vv * 8];
        fx4 p1 = *(const fx4*)&ST[kb * 1024 + vv * 8 + 4];
        #pragma unroll
        for (int e = 0; e < 4; e++){
          bfr[s][nt][e]     = (_Float16)p0[e];
          bfr[s][nt][4 + e] = (_Float16)p1[e];
        }
      }
    #pragma unroll
    for (int s = 0; s < 2; s++)
      #pragma unroll
      for (int nt = 0; nt < 8; nt++)
        acc[nt] = __builtin_amdgcn_mfma_f32_16x16x32_f16(mf[s], bfr[s][nt], acc[nt], 0, 0, 0);
    __syncthreads();   // all ST reads done
    float* dstS = (c + 1 < 32) ? (Sst + ((size_t)(c + 1) * 12 + h) * 8192) : nullptr;
    #pragma unroll
    for (int nt = 0; nt < 8; nt++){
      int vv = nt * 16 + lm;
      #pragma unroll
      for (int j = 0; j < 4; j++){
        int r = w * 16 + lg * 4 + j;
        ST[(r >> 3) * 1024 + vv * 8 + (r & 7)] = acc[nt][j];
        if (dstS) dstS[(size_t)r * 128 + vv] = acc[nt][j];
      }
    }
    __syncthreads();
  }
}

// ---------------------------------------------------------------- phase C: chunk outputs
__global__ __launch_bounds__(256)
void phaseC(const float* __restrict__ qp, const float* __restrict__ Sst,
            const float* __restrict__ Wt, const float* __restrict__ Uvv,
            const float* __restrict__ Ca, const float* __restrict__ bv,
            float* __restrict__ oraw)
{
  const int blk = blockIdx.x;
  const int h = blk % 12, c = blk / 12, t0 = c * 64;
  const int tid = threadIdx.x;

  __shared__ __align__(16) float S0l[8192];
  __shared__ __align__(16) float Ul[8192];
  __shared__ __align__(16) float Wl[4096];
  __shared__ __align__(16) float Ql[4096];
  __shared__ float bl[64];

  #pragma unroll
  for (int e = 0; e < 8; e++){
    int i4 = tid + e * 256;
    *(fx4*)&S0l[i4 * 4] = *(const fx4*)(Sst + (size_t)blk * 8192 + i4 * 4);
    *(fx4*)&Ul[i4 * 4]  = *(const fx4*)(Uvv + (size_t)blk * 8192 + i4 * 4);
  }
  #pragma unroll
  for (int e = 0; e < 4; e++){
    int i4 = tid + e * 256;
    *(fx4*)&Wl[i4 * 4] = *(const fx4*)(Wt + (size_t)blk * 4096 + i4 * 4);
  }
  {
    int i = tid >> 2, q4 = tid & 3;
    const float* src = qp + (size_t)(t0 + i) * 768 + h * 64 + q4 * 16;
    #pragma unroll
    for (int e = 0; e < 4; e++)
      *(fx4*)&Ql[i * 64 + q4 * 16 + e * 4] = *(const fx4*)(src + e * 4);
  }
  if (tid < 64) bl[tid] = bv[(size_t)blk * 64 + tid];
  __syncthreads();

  const int v = tid & 127, rh = tid >> 7;
  float s0c[64];
  #pragma unroll
  for (int d = 0; d < 64; d++) s0c[d] = S0l[d * 128 + v];

  // U = Uv - W @ S0
  for (int j = rh * 32; j < rh * 32 + 32; j++){
    float accv = 0.f;
    #pragma unroll
    for (int d = 0; d < 64; d++) accv += Wl[j * 64 + d] * s0c[d];
    Ul[j * 128 + v] -= accv;
  }
  __syncthreads();
  #pragma unroll
  for (int e = 0; e < 4; e++){   // Cattn into Wl
    int i4 = tid + e * 256;
    *(fx4*)&Wl[i4 * 4] = *(const fx4*)(Ca + (size_t)blk * 4096 + i4 * 4);
  }
  __syncthreads();

  // o_i = b_i * q_i S0 + sum_{j<=i} Cattn_ij U_j
  for (int i = rh * 32; i < rh * 32 + 32; i++){
    float aq = 0.f;
    #pragma unroll
    for (int d = 0; d < 64; d++) aq += Ql[i * 64 + d] * s0c[d];
    float ao = 0.f;
    for (int j = 0; j <= i; j++) ao += Wl[i * 64 + j] * Ul[j * 128 + v];
    oraw[(size_t)(t0 + i) * 1536 + h * 128 + v] = bl[i] * aq + ao;
  }
}

// ---------------------------------------------------------------- RMSNorm * g_norm_w * silu(g)
__global__ __launch_bounds__(64)
void rmsgate(const float* __restrict__ oraw, const float* __restrict__ gx,
             const float* __restrict__ gnw, float* __restrict__ og)
{
  int t = blockIdx.x, h = blockIdx.y, lane = threadIdx.x;
  size_t base = (size_t)t * 1536 + h * 128;
  float o1 = oraw[base + lane], o2 = oraw[base + 64 + lane];
  float ss = o1 * o1 + o2 * o2;
  #pragma unroll
  for (int d = 1; d < 64; d <<= 1) ss += __shfl_xor(ss, d, 64);
  float r = rsqrtf(ss * (1.f / 128.f) + 1e-5f);
  float g1 = gx[base + lane], g2 = gx[base + 64 + lane];
  og[base + lane]      = o1 * r * gnw[lane]      * (g1 / (1.f + expf(-g1)));
  og[base + 64 + lane] = o2 * r * gnw[64 + lane] * (g2 / (1.f + expf(-g2)));
}

// ---------------------------------------------------------------- launcher
extern "C" void kernel_launch(void* const* d_in, const int* in_sizes, int n_in,
                              void* d_out, int out_size, void* d_ws, size_t ws_size,
                              hipStream_t stream)
{
  const int*   ids   = (const int*)d_in[0];
  const float* emb   = (const float*)d_in[1];
  const float* Wq    = (const float*)d_in[2];
  const float* Wk    = (const float*)d_in[3];
  const float* Wv    = (const float*)d_in[4];
  const float* Wg    = (const float*)d_in[5];
  const float* wqc   = (const float*)d_in[6];
  const float* wkc   = (const float*)d_in[7];
  const float* wvc   = (const float*)d_in[8];
  const float* Wgk   = (const float*)d_in[9];
  const float* Wb    = (const float*)d_in[10];
  const float* b_b   = (const float*)d_in[11];
  const float* A_log = (const float*)d_in[12];
  const float* dtb   = (const float*)d_in[13];
  const float* gnw   = (const float*)d_in[14];
  const float* Wo    = (const float*)d_in[15];
  const float* Wlm   = (const float*)d_in[16];
  const float* b_lm  = (const float*)d_in[17];
  float* out = (float*)d_out;

  // d_out (102.9M floats) doubles as scratch: everything below is dead before
  // the final LM GEMM overwrites all of d_out (it reads only hbuf in d_ws).
  float* x    = out;               // 2048x1024
  float* qx   = out + 2097152;     // 2048x768
  float* kx   = out + 3670016;     // 2048x768
  float* vx   = out + 5242880;     // 2048x1536
  float* gx   = out + 8388608;     // 2048x1536 (kept until rmsgate)
  float* qpp  = out + 11534336;    // 2048x768
  float* kpp  = out + 13107200;    // 2048x768
  float* vpp  = out + 14680064;    // 2048x1536
  float* gkb  = out + 17825792;    // 2048x12
  float* bet  = out + 17850368;    // 2048x12
  float* Wt   = out + 17874944;    // 384x64x64
  float* Uvv  = out + 19447808;    // 384x64x128
  float* Mg   = out + 22593536;    // 384x64x64
  float* Ng   = out + 24166400;    // 384x64x128
  float* Ca   = out + 27312128;    // 384x64x64
  float* bvv  = out + 28884992;    // 384x64
  float* Sst  = out + 28909568;    // 384x64x128 (chunk-start states)
  float* oraw = out + 32055296;    // 2048x1536
  float* og   = out + 35201024;    // 2048x1536
  float* hbuf = (float*)d_ws;      // 2048x1024 (must survive the LM GEMM)

  embed_k<<<2048, 256, 0, stream>>>(ids, emb, x);
  gemm_bt<<<dim3(16, 6),  256, 0, stream>>>(x, Wq, qx, nullptr, 2048, 768, 1024);
  gemm_bt<<<dim3(16, 6),  256, 0, stream>>>(x, Wk, kx, nullptr, 2048, 768, 1024);
  gemm_bt<<<dim3(16, 12), 256, 0, stream>>>(x, Wv, vx, nullptr, 2048, 1536, 1024);
  gemm_bt<<<dim3(16, 12), 256, 0, stream>>>(x, Wg, gx, nullptr, 2048, 1536, 1024);
  gkbeta_k<<<dim3(2048, 12), 64, 0, stream>>>(x, Wgk, Wb, b_b, A_log, dtb, gkb, bet);
  conv_silu<<<dim3(2048, 12), 64, 0, stream>>>(qx, wqc, qpp, 768, 1, 0.125f);
  conv_silu<<<dim3(2048, 12), 64, 0, stream>>>(kx, wkc, kpp, 768, 1, 1.0f);
  conv_silu<<<dim3(2048, 24), 64, 0, stream>>>(vx, wvc, vpp, 1536, 0, 1.0f);
  phaseA<<<384, 256, 0, stream>>>(qpp, kpp, vpp, gkb, bet, Wt, Uvv, Mg, Ng, Ca, bvv);
  phaseB<<<12, 256, 0, stream>>>(Mg, Ng, Sst);
  phaseC<<<384, 256, 0, stream>>>(qpp, Sst, Wt, Uvv, Ca, bvv, oraw);
  rmsgate<<<dim3(2048, 12), 64, 0, stream>>>(oraw, gx, gnw, og);
  gemm_bt<<<dim3(16, 8),   256, 0, stream>>>(og, Wo, hbuf, nullptr, 2048, 1024, 1536);
  gemm_bt<<<dim3(16, 393), 256, 0, stream>>>(hbuf, Wlm, out, b_lm, 2048, 50257, 1024);
}

// Round 2
// 1209.775 us; speedup vs baseline: 1.2477x; 1.2477x over previous
//
#include <hip/hip_runtime.h>
#include <math.h>

typedef float fx4 __attribute__((ext_vector_type(4)));
typedef _Float16 hx8 __attribute__((ext_vector_type(8)));
typedef _Float16 hx4 __attribute__((ext_vector_type(4)));

// ---------------------------------------------------------------- embed gather (fp32 + fp16)
__global__ __launch_bounds__(256)
void embed_k(const int* __restrict__ ids, const float* __restrict__ emb,
             float* __restrict__ x, _Float16* __restrict__ xh)
{
  int t = blockIdx.x;
  int id = ids[t];
  fx4 v = *(const fx4*)(emb + (size_t)id * 1024 + threadIdx.x * 4);
  *(fx4*)(x + (size_t)t * 1024 + threadIdx.x * 4) = v;
  hx4 h;
  #pragma unroll
  for (int e = 0; e < 4; e++) h[e] = (_Float16)v[e];
  *(hx4*)(xh + (size_t)t * 1024 + threadIdx.x * 4) = h;
}

// ---------------------------------------------------------------- unified GEMM
// C[M,N] = A[M,K](fp16) @ B[N,K](fp32)^T (+bias); f16 MFMA, fp32 accum.
// 128x128 tile, BK=64, 4 waves, single-buffer LDS (32KB), 2 barriers/K-step,
// prefetch issued between barriers (drains under MFMA), XCD-swizzled blocks,
// LDS-staged coalesced fp32 epilogue (or direct fp16 store when OUT16).
template<bool OUT16>
__global__ __launch_bounds__(256, 3)
void gemm16(const _Float16* __restrict__ A, const float* __restrict__ B,
            void* __restrict__ Cv, const float* __restrict__ bias,
            int M, int N, int K)
{
  __shared__ __align__(16) char smem[32768];
  hx8*   lA = (hx8*)smem;              // [koct 0..7][row 0..127]
  hx8*   lB = (hx8*)(smem + 16384);
  float* eb = (float*)smem;            // epilogue stage 32x132

  const int tid = threadIdx.x;
  const int nwgx = gridDim.x;
  const int nwg  = nwgx * gridDim.y;
  int orig = blockIdx.y * nwgx + blockIdx.x;
  int logical = (orig & 7) * (nwg >> 3) + (orig >> 3);   // nwg % 8 == 0 always here
  const int bx = logical % nwgx, by = logical / nwgx;
  const int m0 = bx << 7, n0 = by << 7;

  const int row = tid & 127, kh = tid >> 7;
  int brI = n0 + row; if (brI > N - 1) brI = N - 1;      // clamp; masked at store
  const _Float16* pa = A + (size_t)(m0 + row) * K;       // + (2j+kh)*8 + kt*64
  const float*    pb = B + (size_t)brI * K + (kh << 5);  // + kt*64 + q*4

  const int lane = tid & 63, w = tid >> 6, wr = w >> 1, wc = w & 1;
  const int lm = lane & 15, lg = lane >> 4;
  const int nk = K >> 6;

  hx8 ra[4];
  fx4 rb[8];
  #pragma unroll
  for (int j = 0; j < 4; j++) ra[j] = *(const hx8*)(pa + (2*j + kh) * 8);
  #pragma unroll
  for (int q = 0; q < 8; q++) rb[q] = *(const fx4*)(pb + q * 4);

  fx4 acc[4][4];
  #pragma unroll
  for (int mt = 0; mt < 4; mt++)
    #pragma unroll
    for (int nt = 0; nt < 4; nt++)
      acc[mt][nt] = (fx4){0.f, 0.f, 0.f, 0.f};

  for (int kt = 0; kt < nk; kt++){
    // stage current tile to LDS
    #pragma unroll
    for (int j = 0; j < 4; j++) lA[(2*j + kh)*128 + row] = ra[j];
    #pragma unroll
    for (int o = 0; o < 4; o++){
      hx8 hb;
      #pragma unroll
      for (int e = 0; e < 4; e++){
        hb[e]     = (_Float16)rb[o*2][e];
        hb[4 + e] = (_Float16)rb[o*2+1][e];
      }
      lB[(kh*4 + o)*128 + row] = hb;
    }
    __syncthreads();                       // barrier1: LDS writes visible (lgkm only)

    if (kt + 1 < nk){                      // prefetch next tile; drains at barrier2 under MFMA
      const _Float16* qa = pa + (kt + 1) * 64;
      const float*    qb = pb + (kt + 1) * 64;
      #pragma unroll
      for (int j = 0; j < 4; j++) ra[j] = *(const hx8*)(qa + (2*j + kh) * 8);
      #pragma unroll
      for (int q = 0; q < 8; q++) rb[q] = *(const fx4*)(qb + q * 4);
    }

    #pragma unroll
    for (int s = 0; s < 2; s++){
      hx8 af[4], bfr[4];
      #pragma unroll
      for (int mt = 0; mt < 4; mt++)
        af[mt] = lA[(s*4 + lg)*128 + wr*64 + mt*16 + lm];
      #pragma unroll
      for (int nt = 0; nt < 4; nt++)
        bfr[nt] = lB[(s*4 + lg)*128 + wc*64 + nt*16 + lm];
      #pragma unroll
      for (int mt = 0; mt < 4; mt++)
        #pragma unroll
        for (int nt = 0; nt < 4; nt++)
          acc[mt][nt] = __builtin_amdgcn_mfma_f32_16x16x32_f16(af[mt], bfr[nt], acc[mt][nt], 0, 0, 0);
    }
    __syncthreads();                       // barrier2: reads done, prefetch drained
  }

  if (OUT16){
    _Float16* Ch = (_Float16*)Cv;
    #pragma unroll
    for (int nt = 0; nt < 4; nt++){
      int col = n0 + wc*64 + nt*16 + lm;
      #pragma unroll
      for (int mt = 0; mt < 4; mt++){
        int r0 = m0 + wr*64 + mt*16 + (lg << 2);
        #pragma unroll
        for (int j = 0; j < 4; j++)
          Ch[(size_t)(r0 + j) * N + col] = (_Float16)acc[mt][nt][j];
      }
    }
  } else {
    float* C = (float*)Cv;
    #pragma unroll
    for (int mt = 0; mt < 4; mt++){
      __syncthreads();
      #pragma unroll
      for (int nt = 0; nt < 4; nt++){
        int c = wc*64 + nt*16 + lm;
        int gc = n0 + c;
        float bsv = bias ? bias[gc < N ? gc : N - 1] : 0.f;
        #pragma unroll
        for (int j = 0; j < 4; j++)
          eb[(wr*16 + lg*4 + j)*132 + c] = acc[mt][nt][j] + bsv;
      }
      __syncthreads();
      #pragma unroll
      for (int i = 0; i < 16; i++){
        int f = tid + i * 256;
        int lrow = f >> 7, c = f & 127;
        int grow = m0 + mt*16 + (lrow & 15) + (lrow >> 4) * 64;
        int gc = n0 + c;
        if (gc < N) C[(size_t)grow * N + gc] = eb[lrow*132 + c];
      }
    }
  }
}

// ---------------------------------------------------------------- gk / beta
__global__ __launch_bounds__(64)
void gkbeta_k(const float* __restrict__ x, const float* __restrict__ Wgk,
              const float* __restrict__ Wb, const float* __restrict__ b_b,
              const float* __restrict__ A_log, const float* __restrict__ dtb,
              float* __restrict__ gko, float* __restrict__ beto)
{
  int t = blockIdx.x, h = blockIdx.y, lane = threadIdx.x;
  const float* xr = x + (size_t)t * 1024;
  float a = 0.f, b = 0.f;
  #pragma unroll
  for (int j = 0; j < 16; j++){
    int idx = lane + j * 64;
    float xv = xr[idx];
    a += xv * Wgk[h * 1024 + idx];
    b += xv * Wb [h * 1024 + idx];
  }
  #pragma unroll
  for (int d = 1; d < 64; d <<= 1){
    a += __shfl_xor(a, d, 64);
    b += __shfl_xor(b, d, 64);
  }
  if (lane == 0){
    float z = a + dtb[h];
    float sp = (z > 20.f) ? z : log1pf(expf(z));
    gko [(size_t)t * 12 + h] = -expf(A_log[h]) * sp;
    beto[(size_t)t * 12 + h] = 1.f / (1.f + expf(-(b + b_b[h])));
  }
}

// ---------------------------------------------------------------- conv + silu (+l2norm)
__global__ __launch_bounds__(64)
void conv_silu(const float* __restrict__ in, const float* __restrict__ cw,
               float* __restrict__ outp, int D, int donorm, float scale)
{
  int t = blockIdx.x, hg = blockIdx.y, lane = threadIdx.x;
  int ch = hg * 64 + lane;
  float y = 0.f;
  #pragma unroll
  for (int i = 0; i < 4; i++){
    int ts = t - 3 + i;
    if (ts >= 0) y += cw[ch * 4 + i] * in[(size_t)ts * D + ch];
  }
  y = y / (1.f + expf(-y));                 // silu
  if (donorm){
    float ss = y * y;
    #pragma unroll
    for (int d = 1; d < 64; d <<= 1) ss += __shfl_xor(ss, d, 64);
    y *= rsqrtf(ss + 1e-6f) * scale;        // l2norm over head (+q scale)
  }
  outp[(size_t)t * D + ch] = y;
}

// ---------------------------------------------------------------- phase A: per-(head,chunk) WY factors
__global__ __launch_bounds__(256)
void phaseA(const float* __restrict__ qp, const float* __restrict__ kp,
            const float* __restrict__ vp, const float* __restrict__ gkv,
            const float* __restrict__ bev, float* __restrict__ Wt,
            float* __restrict__ Uvv, float* __restrict__ Mg,
            float* __restrict__ Ng, float* __restrict__ Ca,
            float* __restrict__ bv)
{
  const int blk = blockIdx.x;
  const int h = blk % 12, c = blk / 12, t0 = c * 64;
  const int tid = threadIdx.x;

  __shared__ __align__(16) float Kc[4096];     // K chunk [64][64]
  __shared__ __align__(16) float X[12288];     // [64][192]: cols 0..127 Uv, 128..191 W
  __shared__ float Pp[2016];                   // packed strict-lower P
  __shared__ float gt[64], bb[64], be[64], eg[64];
  __shared__ float Gtot;

  { // load K chunk
    int i = tid >> 2, q4 = tid & 3;
    const float* src = kp + (size_t)(t0 + i) * 768 + h * 64 + q4 * 16;
    #pragma unroll
    for (int e = 0; e < 4; e++)
      *(fx4*)&Kc[i * 64 + q4 * 16 + e * 4] = *(const fx4*)(src + e * 4);
  }
  if (tid < 64){ // within-chunk cumulative log-decay
    float g = gkv[(size_t)(t0 + tid) * 12 + h];
    #pragma unroll
    for (int d = 1; d < 64; d <<= 1){
      float ts = __shfl_up(g, d, 64);
      if (tid >= d) g += ts;
    }
    gt[tid] = g;
    bb[tid] = expf(g);
    be[tid] = bev[(size_t)(t0 + tid) * 12 + h];
    if (tid == 63) Gtot = g;
  }
  __syncthreads();
  const float GT = Gtot;
  if (tid < 64) eg[tid] = expf(GT - gt[tid]);

  { // P_ij = beta_i * (k_i.k_j) * exp(gt_i - gt_j), j < i
    int i = tid >> 2, jb = tid & 3;
    float ki[64];
    #pragma unroll
    for (int d = 0; d < 64; d++) ki[d] = Kc[i * 64 + d];
    float gi = gt[i], bei = be[i];
    int pbase = (i * (i - 1)) >> 1;
    for (int jj = 0; jj < 16; jj++){
      int j = jb * 16 + jj;
      if (j < i){
        float dot = 0.f;
        #pragma unroll
        for (int d = 0; d < 64; d++) dot += ki[d] * Kc[j * 64 + d];
        Pp[pbase + j] = bei * dot * expf(gi - gt[j]);
      }
    }
  }
  { // X init = diag(beta)[V | diag(b)K]
    int i = tid >> 2, seg = tid & 3;
    float bei = be[i], bbi = bb[i];
    #pragma unroll
    for (int u = 0; u < 12; u++){
      int colv = seg * 48 + u * 4;
      fx4 val;
      if (colv < 128){
        val = *(const fx4*)(vp + (size_t)(t0 + i) * 1536 + h * 128 + colv);
        #pragma unroll
        for (int e = 0; e < 4; e++) val[e] *= bei;
      } else {
        int d0 = colv - 128;
        #pragma unroll
        for (int e = 0; e < 4; e++) val[e] = bei * bbi * Kc[i * 64 + d0 + e];
      }
      *(fx4*)&X[i * 192 + colv] = val;
    }
  }
  __syncthreads();

  // forward substitution: X <- (I+P)^-1 X
  for (int i = 1; i < 64; i++){
    if (tid < 192){
      int pbase = (i * (i - 1)) >> 1;
      float accv = 0.f;
      for (int j = 0; j < i; j++) accv += Pp[pbase + j] * X[j * 192 + tid];
      X[i * 192 + tid] -= accv;
    }
    __syncthreads();
  }

  // store Uv, W
  for (int e = tid; e < 12288; e += 256){
    int i = e / 192, colv = e - i * 192;
    float xv = X[e];
    if (colv < 128) Uvv[(size_t)blk * 8192 + i * 128 + colv] = xv;
    else            Wt [(size_t)blk * 4096 + i * 64 + (colv - 128)] = xv;
  }

  { // M = exp(G) I - K'^T W
    int d2 = tid & 63, d1b = tid >> 6;
    for (int ii = 0; ii < 16; ii++){
      int d1 = d1b * 16 + ii;
      float s = 0.f;
      for (int j = 0; j < 64; j++)
        s += eg[j] * Kc[j * 64 + d1] * X[j * 192 + 128 + d2];
      Mg[(size_t)blk * 4096 + d1 * 64 + d2] = ((d1 == d2) ? expf(GT) : 0.f) - s;
    }
  }
  { // N = K'^T Uv
    int vv = tid & 127, d1b = tid >> 7;
    for (int ii = 0; ii < 32; ii++){
      int d1 = d1b * 32 + ii;
      float s = 0.f;
      for (int j = 0; j < 64; j++)
        s += eg[j] * Kc[j * 64 + d1] * X[j * 192 + vv];
      Ng[(size_t)blk * 8192 + d1 * 128 + vv] = s;
    }
  }
  { // Cattn_ij = (q_i.k_j) exp(gt_i-gt_j), j <= i
    int i = tid >> 2, jb = tid & 3;
    float qi[64];
    {
      const float* src = qp + (size_t)(t0 + i) * 768 + h * 64;
      #pragma unroll
      for (int q4 = 0; q4 < 16; q4++){
        fx4 t4 = *(const fx4*)(src + q4 * 4);
        #pragma unroll
        for (int e = 0; e < 4; e++) qi[q4 * 4 + e] = t4[e];
      }
    }
    float gi = gt[i];
    for (int jj = 0; jj < 16; jj++){
      int j = jb * 16 + jj;
      float outv = 0.f;
      if (j <= i){
        float dot = 0.f;
        #pragma unroll
        for (int d = 0; d < 64; d++) dot += qi[d] * Kc[j * 64 + d];
        outv = dot * expf(gi - gt[j]);
      }
      Ca[(size_t)blk * 4096 + i * 64 + j] = outv;
    }
  }
  if (tid < 64) bv[(size_t)blk * 64 + tid] = bb[tid];
}

// ---------------------------------------------------------------- phase B: sequential S <- M S + N (per head)
__global__ __launch_bounds__(256)
void phaseB(const float* __restrict__ Mg, const float* __restrict__ Ng,
            float* __restrict__ Sst)
{
  const int h = blockIdx.x;
  const int tid = threadIdx.x, lane = tid & 63, w = tid >> 6;
  const int lm = lane & 15, lg = lane >> 4;
  __shared__ __align__(16) float ST[8192];   // S in [k-octet][v][8] layout

  #pragma unroll
  for (int e = 0; e < 8; e++)
    *(fx4*)&ST[(tid + e * 256) * 4] = (fx4){0.f,0.f,0.f,0.f};
  {
    float* dst = Sst + (size_t)h * 8192;     // S_states[0] = 0
    #pragma unroll
    for (int e = 0; e < 8; e++)
      *(fx4*)(dst + (size_t)(tid + e * 256) * 4) = (fx4){0.f,0.f,0.f,0.f};
  }
  __syncthreads();

  fx4 rm[2][2];
  float rn[8][4];
  auto loadMN = [&](int cc){
    const float* mb = Mg + ((size_t)cc * 12 + h) * 4096 + (w * 16 + lm) * 64 + lg * 8;
    rm[0][0] = *(const fx4*)(mb);
    rm[0][1] = *(const fx4*)(mb + 4);
    rm[1][0] = *(const fx4*)(mb + 32);
    rm[1][1] = *(const fx4*)(mb + 36);
    const float* nb = Ng + ((size_t)cc * 12 + h) * 8192;
    #pragma unroll
    for (int nt = 0; nt < 8; nt++)
      #pragma unroll
      for (int j = 0; j < 4; j++)
        rn[nt][j] = nb[(w * 16 + lg * 4 + j) * 128 + nt * 16 + lm];
  };
  loadMN(0);

  for (int c = 0; c < 32; c++){
    hx8 mf[2];
    #pragma unroll
    for (int s = 0; s < 2; s++)
      #pragma unroll
      for (int e = 0; e < 4; e++){
        mf[s][e]     = (_Float16)rm[s][0][e];
        mf[s][4 + e] = (_Float16)rm[s][1][e];
      }
    fx4 acc[8];
    #pragma unroll
    for (int nt = 0; nt < 8; nt++)
      #pragma unroll
      for (int j = 0; j < 4; j++) acc[nt][j] = rn[nt][j];
    if (c + 1 < 32) loadMN(c + 1);

    hx8 bfr[2][8];
    #pragma unroll
    for (int s = 0; s < 2; s++)
      #pragma unroll
      for (int nt = 0; nt < 8; nt++){
        int vv = nt * 16 + lm, kb = s * 4 + lg;
        fx4 p0 = *(const fx4*)&ST[kb * 1024 + vv * 8];
        fx4 p1 = *(const fx4*)&ST[kb * 1024 + vv * 8 + 4];
        #pragma unroll
        for (int e = 0; e < 4; e++){
          bfr[s][nt][e]     = (_Float16)p0[e];
          bfr[s][nt][4 + e] = (_Float16)p1[e];
        }
      }
    #pragma unroll
    for (int s = 0; s < 2; s++)
      #pragma unroll
      for (int nt = 0; nt < 8; nt++)
        acc[nt] = __builtin_amdgcn_mfma_f32_16x16x32_f16(mf[s], bfr[s][nt], acc[nt], 0, 0, 0);
    __syncthreads();   // all ST reads done
    float* dstS = (c + 1 < 32) ? (Sst + ((size_t)(c + 1) * 12 + h) * 8192) : nullptr;
    #pragma unroll
    for (int nt = 0; nt < 8; nt++){
      int vv = nt * 16 + lm;
      #pragma unroll
      for (int j = 0; j < 4; j++){
        int r = w * 16 + lg * 4 + j;
        ST[(r >> 3) * 1024 + vv * 8 + (r & 7)] = acc[nt][j];
        if (dstS) dstS[(size_t)r * 128 + vv] = acc[nt][j];
      }
    }
    __syncthreads();
  }
}

// ---------------------------------------------------------------- phase C: chunk outputs
__global__ __launch_bounds__(256)
void phaseC(const float* __restrict__ qp, const float* __restrict__ Sst,
            const float* __restrict__ Wt, const float* __restrict__ Uvv,
            const float* __restrict__ Ca, const float* __restrict__ bv,
            float* __restrict__ oraw)
{
  const int blk = blockIdx.x;
  const int h = blk % 12, c = blk / 12, t0 = c * 64;
  const int tid = threadIdx.x;

  __shared__ __align__(16) float S0l[8192];
  __shared__ __align__(16) float Ul[8192];
  __shared__ __align__(16) float Wl[4096];
  __shared__ __align__(16) float Ql[4096];
  __shared__ float bl[64];

  #pragma unroll
  for (int e = 0; e < 8; e++){
    int i4 = tid + e * 256;
    *(fx4*)&S0l[i4 * 4] = *(const fx4*)(Sst + (size_t)blk * 8192 + i4 * 4);
    *(fx4*)&Ul[i4 * 4]  = *(const fx4*)(Uvv + (size_t)blk * 8192 + i4 * 4);
  }
  #pragma unroll
  for (int e = 0; e < 4; e++){
    int i4 = tid + e * 256;
    *(fx4*)&Wl[i4 * 4] = *(const fx4*)(Wt + (size_t)blk * 4096 + i4 * 4);
  }
  {
    int i = tid >> 2, q4 = tid & 3;
    const float* src = qp + (size_t)(t0 + i) * 768 + h * 64 + q4 * 16;
    #pragma unroll
    for (int e = 0; e < 4; e++)
      *(fx4*)&Ql[i * 64 + q4 * 16 + e * 4] = *(const fx4*)(src + e * 4);
  }
  if (tid < 64) bl[tid] = bv[(size_t)blk * 64 + tid];
  __syncthreads();

  const int v = tid & 127, rh = tid >> 7;
  float s0c[64];
  #pragma unroll
  for (int d = 0; d < 64; d++) s0c[d] = S0l[d * 128 + v];

  // U = Uv - W @ S0
  for (int j = rh * 32; j < rh * 32 + 32; j++){
    float accv = 0.f;
    #pragma unroll
    for (int d = 0; d < 64; d++) accv += Wl[j * 64 + d] * s0c[d];
    Ul[j * 128 + v] -= accv;
  }
  __syncthreads();
  #pragma unroll
  for (int e = 0; e < 4; e++){   // Cattn into Wl
    int i4 = tid + e * 256;
    *(fx4*)&Wl[i4 * 4] = *(const fx4*)(Ca + (size_t)blk * 4096 + i4 * 4);
  }
  __syncthreads();

  // o_i = b_i * q_i S0 + sum_{j<=i} Cattn_ij U_j
  for (int i = rh * 32; i < rh * 32 + 32; i++){
    float aq = 0.f;
    #pragma unroll
    for (int d = 0; d < 64; d++) aq += Ql[i * 64 + d] * s0c[d];
    float ao = 0.f;
    for (int j = 0; j <= i; j++) ao += Wl[i * 64 + j] * Ul[j * 128 + v];
    oraw[(size_t)(t0 + i) * 1536 + h * 128 + v] = bl[i] * aq + ao;
  }
}

// ---------------------------------------------------------------- RMSNorm * g_norm_w * silu(g) -> fp16
__global__ __launch_bounds__(64)
void rmsgate(const float* __restrict__ oraw, const float* __restrict__ gx,
             const float* __restrict__ gnw, _Float16* __restrict__ ogh)
{
  int t = blockIdx.x, h = blockIdx.y, lane = threadIdx.x;
  size_t base = (size_t)t * 1536 + h * 128;
  float o1 = oraw[base + lane], o2 = oraw[base + 64 + lane];
  float ss = o1 * o1 + o2 * o2;
  #pragma unroll
  for (int d = 1; d < 64; d <<= 1) ss += __shfl_xor(ss, d, 64);
  float r = rsqrtf(ss * (1.f / 128.f) + 1e-5f);
  float g1 = gx[base + lane], g2 = gx[base + 64 + lane];
  ogh[base + lane]      = (_Float16)(o1 * r * gnw[lane]      * (g1 / (1.f + expf(-g1))));
  ogh[base + 64 + lane] = (_Float16)(o2 * r * gnw[64 + lane] * (g2 / (1.f + expf(-g2))));
}

// ---------------------------------------------------------------- launcher
extern "C" void kernel_launch(void* const* d_in, const int* in_sizes, int n_in,
                              void* d_out, int out_size, void* d_ws, size_t ws_size,
                              hipStream_t stream)
{
  const int*   ids   = (const int*)d_in[0];
  const float* emb   = (const float*)d_in[1];
  const float* Wq    = (const float*)d_in[2];
  const float* Wk    = (const float*)d_in[3];
  const float* Wv    = (const float*)d_in[4];
  const float* Wg    = (const float*)d_in[5];
  const float* wqc   = (const float*)d_in[6];
  const float* wkc   = (const float*)d_in[7];
  const float* wvc   = (const float*)d_in[8];
  const float* Wgk   = (const float*)d_in[9];
  const float* Wb    = (const float*)d_in[10];
  const float* b_b   = (const float*)d_in[11];
  const float* A_log = (const float*)d_in[12];
  const float* dtb   = (const float*)d_in[13];
  const float* gnw   = (const float*)d_in[14];
  const float* Wo    = (const float*)d_in[15];
  const float* Wlm   = (const float*)d_in[16];
  const float* b_lm  = (const float*)d_in[17];
  float* out = (float*)d_out;

  // d_out (102.9M floats) doubles as scratch: all intermediates die before
  // the final LM GEMM overwrites d_out (it reads only h_h in d_ws).
  float* x    = out;               // 2048x1024 fp32 (for gkbeta)
  float* qx   = out + 2097152;     // 2048x768
  float* kx   = out + 3670016;     // 2048x768
  float* vx   = out + 5242880;     // 2048x1536
  float* gx   = out + 8388608;     // 2048x1536 (kept until rmsgate)
  float* qpp  = out + 11534336;    // 2048x768
  float* kpp  = out + 13107200;    // 2048x768
  float* vpp  = out + 14680064;    // 2048x1536
  float* gkb  = out + 17825792;    // 2048x12
  float* bet  = out + 17850368;    // 2048x12
  float* Wt   = out + 17874944;    // 384x64x64
  float* Uvv  = out + 19447808;    // 384x64x128
  float* Mg   = out + 22593536;    // 384x64x64
  float* Ng   = out + 24166400;    // 384x64x128
  float* Ca   = out + 27312128;    // 384x64x64
  float* bvv  = out + 28884992;    // 384x64
  float* Sst  = out + 28909568;    // 384x64x128 (chunk-start states)
  float* oraw = out + 32055296;    // 2048x1536
  _Float16* x_h  = (_Float16*)(out + 35201024);  // 2048x1024 fp16
  _Float16* og_h = (_Float16*)(out + 36300000);  // 2048x1536 fp16
  _Float16* h_h  = (_Float16*)d_ws;              // 2048x1024 fp16 (survives LM GEMM)

  embed_k<<<2048, 256, 0, stream>>>(ids, emb, x, x_h);
  gemm16<false><<<dim3(16, 6),  256, 0, stream>>>(x_h, Wq, qx, nullptr, 2048, 768, 1024);
  gemm16<false><<<dim3(16, 6),  256, 0, stream>>>(x_h, Wk, kx, nullptr, 2048, 768, 1024);
  gemm16<false><<<dim3(16, 12), 256, 0, stream>>>(x_h, Wv, vx, nullptr, 2048, 1536, 1024);
  gemm16<false><<<dim3(16, 12), 256, 0, stream>>>(x_h, Wg, gx, nullptr, 2048, 1536, 1024);
  gkbeta_k<<<dim3(2048, 12), 64, 0, stream>>>(x, Wgk, Wb, b_b, A_log, dtb, gkb, bet);
  conv_silu<<<dim3(2048, 12), 64, 0, stream>>>(qx, wqc, qpp, 768, 1, 0.125f);
  conv_silu<<<dim3(2048, 12), 64, 0, stream>>>(kx, wkc, kpp, 768, 1, 1.0f);
  conv_silu<<<dim3(2048, 24), 64, 0, stream>>>(vx, wvc, vpp, 1536, 0, 1.0f);
  phaseA<<<384, 256, 0, stream>>>(qpp, kpp, vpp, gkb, bet, Wt, Uvv, Mg, Ng, Ca, bvv);
  phaseB<<<12, 256, 0, stream>>>(Mg, Ng, Sst);
  phaseC<<<384, 256, 0, stream>>>(qpp, Sst, Wt, Uvv, Ca, bvv, oraw);
  rmsgate<<<dim3(2048, 12), 64, 0, stream>>>(oraw, gx, gnw, og_h);
  gemm16<true><<<dim3(16, 8),   256, 0, stream>>>(og_h, Wo, h_h, nullptr, 2048, 1024, 1536);
  gemm16<false><<<dim3(16, 393), 256, 0, stream>>>(h_h, Wlm, out, b_lm, 2048, 50257, 1024);
}

// Round 3
// 1076.781 us; speedup vs baseline: 1.4018x; 1.1235x over previous
//
#include <hip/hip_runtime.h>
#include <math.h>

typedef float fx4 __attribute__((ext_vector_type(4)));
typedef _Float16 hx8 __attribute__((ext_vector_type(8)));
typedef _Float16 hx4 __attribute__((ext_vector_type(4)));

// ---------------------------------------------------------------- embed gather (fp32 + fp16)
__global__ __launch_bounds__(256)
void embed_k(const int* __restrict__ ids, const float* __restrict__ emb,
             float* __restrict__ x, _Float16* __restrict__ xh)
{
  int t = blockIdx.x;
  int id = ids[t];
  fx4 v = *(const fx4*)(emb + (size_t)id * 1024 + threadIdx.x * 4);
  *(fx4*)(x + (size_t)t * 1024 + threadIdx.x * 4) = v;
  hx4 h;
  #pragma unroll
  for (int e = 0; e < 4; e++) h[e] = (_Float16)v[e];
  *(hx4*)(xh + (size_t)t * 1024 + threadIdx.x * 4) = h;
}

// ---------------------------------------------------------------- unified GEMM
// C[M,N] = A[M,K](fp16) @ B[N,K](fp32)^T (+bias); f16 MFMA, fp32 accum.
// 128x128 tile, BK=64, 4 waves, single-buffer LDS, 2 barriers/K-step,
// prefetch between barriers. Staging loads are LANE-CONTIGUOUS within a row
// (8 lanes cover one row's 64-elem K-slab) so each VMEM instr touches ~8
// cache lines instead of 64 (the R2 bottleneck). Each thread owns one
// K-octet -> single b128 write into the conflict-free [oct][row] layout.
template<bool OUT16>
__global__ __launch_bounds__(256, 3)
void gemm16(const _Float16* __restrict__ A, const float* __restrict__ B,
            void* __restrict__ Cv, const float* __restrict__ bias,
            int M, int N, int K)
{
  __shared__ __align__(16) char smem[32768];
  hx8*   lA = (hx8*)smem;              // [oct 0..7][row 0..127]
  hx8*   lB = (hx8*)(smem + 16384);
  float* eb = (float*)smem;            // epilogue stage 32x132

  const int tid = threadIdx.x;
  const int nwgx = gridDim.x;
  const int nwg  = nwgx * gridDim.y;
  int orig = blockIdx.y * nwgx + blockIdx.x;
  int logical = (orig & 7) * (nwg >> 3) + (orig >> 3);   // nwg % 8 == 0 always here
  const int bx = logical % nwgx, by = logical / nwgx;
  const int m0 = bx << 7, n0 = by << 7;

  const int lane = tid & 63, w = tid >> 6, wr = w >> 1, wc = w & 1;
  const int lm = lane & 15, lg = lane >> 4;
  const int nk = K >> 6;

  // coalesced staging addresses: thread -> (row = j*32 + tid>>3, oct = tid&7)
  const int srow = tid >> 3, soct = tid & 7;
  const _Float16* pa[4];
  const float*    pb[4];
  #pragma unroll
  for (int j = 0; j < 4; j++){
    int r = m0 + j * 32 + srow;
    pa[j] = A + (size_t)r * K + soct * 8;
  }
  #pragma unroll
  for (int j = 0; j < 4; j++){
    int r = n0 + j * 32 + srow; if (r > N - 1) r = N - 1;  // clamp; masked at store
    pb[j] = B + (size_t)r * K + soct * 8;
  }

  hx8 ra[4];
  fx4 rb[4][2];
  #pragma unroll
  for (int j = 0; j < 4; j++){
    ra[j]    = *(const hx8*)(pa[j]);
    rb[j][0] = *(const fx4*)(pb[j]);
    rb[j][1] = *(const fx4*)(pb[j] + 4);
  }

  fx4 acc[4][4];
  #pragma unroll
  for (int mt = 0; mt < 4; mt++)
    #pragma unroll
    for (int nt = 0; nt < 4; nt++)
      acc[mt][nt] = (fx4){0.f, 0.f, 0.f, 0.f};

  for (int kt = 0; kt < nk; kt++){
    // stage current tile to LDS (one b128 per thread per j)
    #pragma unroll
    for (int j = 0; j < 4; j++)
      lA[soct * 128 + j * 32 + srow] = ra[j];
    #pragma unroll
    for (int j = 0; j < 4; j++){
      hx8 hb;
      #pragma unroll
      for (int e = 0; e < 4; e++){
        hb[e]     = (_Float16)rb[j][0][e];
        hb[4 + e] = (_Float16)rb[j][1][e];
      }
      lB[soct * 128 + j * 32 + srow] = hb;
    }
    __syncthreads();                       // barrier1: LDS writes visible

    if (kt + 1 < nk){                      // prefetch next K-slab (coalesced)
      #pragma unroll
      for (int j = 0; j < 4; j++){
        ra[j]    = *(const hx8*)(pa[j] + (kt + 1) * 64);
        rb[j][0] = *(const fx4*)(pb[j] + (kt + 1) * 64);
        rb[j][1] = *(const fx4*)(pb[j] + (kt + 1) * 64 + 4);
      }
    }

    #pragma unroll
    for (int s = 0; s < 2; s++){
      hx8 af[4], bfr[4];
      #pragma unroll
      for (int mt = 0; mt < 4; mt++)
        af[mt] = lA[(s*4 + lg)*128 + wr*64 + mt*16 + lm];
      #pragma unroll
      for (int nt = 0; nt < 4; nt++)
        bfr[nt] = lB[(s*4 + lg)*128 + wc*64 + nt*16 + lm];
      #pragma unroll
      for (int mt = 0; mt < 4; mt++)
        #pragma unroll
        for (int nt = 0; nt < 4; nt++)
          acc[mt][nt] = __builtin_amdgcn_mfma_f32_16x16x32_f16(af[mt], bfr[nt], acc[mt][nt], 0, 0, 0);
    }
    __syncthreads();                       // barrier2: reads done, prefetch drained
  }

  if (OUT16){
    _Float16* Ch = (_Float16*)Cv;
    #pragma unroll
    for (int nt = 0; nt < 4; nt++){
      int col = n0 + wc*64 + nt*16 + lm;
      #pragma unroll
      for (int mt = 0; mt < 4; mt++){
        int r0 = m0 + wr*64 + mt*16 + (lg << 2);
        #pragma unroll
        for (int j = 0; j < 4; j++)
          Ch[(size_t)(r0 + j) * N + col] = (_Float16)acc[mt][nt][j];
      }
    }
  } else {
    float* C = (float*)Cv;
    #pragma unroll
    for (int mt = 0; mt < 4; mt++){
      __syncthreads();
      #pragma unroll
      for (int nt = 0; nt < 4; nt++){
        int c = wc*64 + nt*16 + lm;
        int gc = n0 + c;
        float bsv = bias ? bias[gc < N ? gc : N - 1] : 0.f;
        #pragma unroll
        for (int j = 0; j < 4; j++)
          eb[(wr*16 + lg*4 + j)*132 + c] = acc[mt][nt][j] + bsv;
      }
      __syncthreads();
      #pragma unroll
      for (int i = 0; i < 16; i++){
        int f = tid + i * 256;
        int lrow = f >> 7, c = f & 127;
        int grow = m0 + mt*16 + (lrow & 15) + (lrow >> 4) * 64;
        int gc = n0 + c;
        if (gc < N) C[(size_t)grow * N + gc] = eb[lrow*132 + c];
      }
    }
  }
}

// ---------------------------------------------------------------- gk / beta
__global__ __launch_bounds__(64)
void gkbeta_k(const float* __restrict__ x, const float* __restrict__ Wgk,
              const float* __restrict__ Wb, const float* __restrict__ b_b,
              const float* __restrict__ A_log, const float* __restrict__ dtb,
              float* __restrict__ gko, float* __restrict__ beto)
{
  int t = blockIdx.x, h = blockIdx.y, lane = threadIdx.x;
  const float* xr = x + (size_t)t * 1024;
  float a = 0.f, b = 0.f;
  #pragma unroll
  for (int j = 0; j < 16; j++){
    int idx = lane + j * 64;
    float xv = xr[idx];
    a += xv * Wgk[h * 1024 + idx];
    b += xv * Wb [h * 1024 + idx];
  }
  #pragma unroll
  for (int d = 1; d < 64; d <<= 1){
    a += __shfl_xor(a, d, 64);
    b += __shfl_xor(b, d, 64);
  }
  if (lane == 0){
    float z = a + dtb[h];
    float sp = (z > 20.f) ? z : log1pf(expf(z));
    gko [(size_t)t * 12 + h] = -expf(A_log[h]) * sp;
    beto[(size_t)t * 12 + h] = 1.f / (1.f + expf(-(b + b_b[h])));
  }
}

// ---------------------------------------------------------------- conv + silu (+l2norm)
__global__ __launch_bounds__(64)
void conv_silu(const float* __restrict__ in, const float* __restrict__ cw,
               float* __restrict__ outp, int D, int donorm, float scale)
{
  int t = blockIdx.x, hg = blockIdx.y, lane = threadIdx.x;
  int ch = hg * 64 + lane;
  float y = 0.f;
  #pragma unroll
  for (int i = 0; i < 4; i++){
    int ts = t - 3 + i;
    if (ts >= 0) y += cw[ch * 4 + i] * in[(size_t)ts * D + ch];
  }
  y = y / (1.f + expf(-y));                 // silu
  if (donorm){
    float ss = y * y;
    #pragma unroll
    for (int d = 1; d < 64; d <<= 1) ss += __shfl_xor(ss, d, 64);
    y *= rsqrtf(ss + 1e-6f) * scale;        // l2norm over head (+q scale)
  }
  outp[(size_t)t * D + ch] = y;
}

// ---------------------------------------------------------------- phase A: per-(head,chunk) WY factors
__global__ __launch_bounds__(256)
void phaseA(const float* __restrict__ qp, const float* __restrict__ kp,
            const float* __restrict__ vp, const float* __restrict__ gkv,
            const float* __restrict__ bev, float* __restrict__ Wt,
            float* __restrict__ Uvv, float* __restrict__ Mg,
            float* __restrict__ Ng, float* __restrict__ Ca,
            float* __restrict__ bv)
{
  const int blk = blockIdx.x;
  const int h = blk % 12, c = blk / 12, t0 = c * 64;
  const int tid = threadIdx.x;

  __shared__ __align__(16) float Kc[4096];     // K chunk [64][64]
  __shared__ __align__(16) float X[12288];     // [64][192]: cols 0..127 Uv, 128..191 W
  __shared__ float Pp[2016];                   // packed strict-lower P
  __shared__ float gt[64], bb[64], be[64], eg[64];
  __shared__ float Gtot;

  { // load K chunk
    int i = tid >> 2, q4 = tid & 3;
    const float* src = kp + (size_t)(t0 + i) * 768 + h * 64 + q4 * 16;
    #pragma unroll
    for (int e = 0; e < 4; e++)
      *(fx4*)&Kc[i * 64 + q4 * 16 + e * 4] = *(const fx4*)(src + e * 4);
  }
  if (tid < 64){ // within-chunk cumulative log-decay
    float g = gkv[(size_t)(t0 + tid) * 12 + h];
    #pragma unroll
    for (int d = 1; d < 64; d <<= 1){
      float ts = __shfl_up(g, d, 64);
      if (tid >= d) g += ts;
    }
    gt[tid] = g;
    bb[tid] = expf(g);
    be[tid] = bev[(size_t)(t0 + tid) * 12 + h];
    if (tid == 63) Gtot = g;
  }
  __syncthreads();
  const float GT = Gtot;
  if (tid < 64) eg[tid] = expf(GT - gt[tid]);

  { // P_ij = beta_i * (k_i.k_j) * exp(gt_i - gt_j), j < i
    int i = tid >> 2, jb = tid & 3;
    float ki[64];
    #pragma unroll
    for (int d = 0; d < 64; d++) ki[d] = Kc[i * 64 + d];
    float gi = gt[i], bei = be[i];
    int pbase = (i * (i - 1)) >> 1;
    for (int jj = 0; jj < 16; jj++){
      int j = jb * 16 + jj;
      if (j < i){
        float dot = 0.f;
        #pragma unroll
        for (int d = 0; d < 64; d++) dot += ki[d] * Kc[j * 64 + d];
        Pp[pbase + j] = bei * dot * expf(gi - gt[j]);
      }
    }
  }
  { // X init = diag(beta)[V | diag(b)K]
    int i = tid >> 2, seg = tid & 3;
    float bei = be[i], bbi = bb[i];
    #pragma unroll
    for (int u = 0; u < 12; u++){
      int colv = seg * 48 + u * 4;
      fx4 val;
      if (colv < 128){
        val = *(const fx4*)(vp + (size_t)(t0 + i) * 1536 + h * 128 + colv);
        #pragma unroll
        for (int e = 0; e < 4; e++) val[e] *= bei;
      } else {
        int d0 = colv - 128;
        #pragma unroll
        for (int e = 0; e < 4; e++) val[e] = bei * bbi * Kc[i * 64 + d0 + e];
      }
      *(fx4*)&X[i * 192 + colv] = val;
    }
  }
  __syncthreads();

  // forward substitution: X <- (I+P)^-1 X
  for (int i = 1; i < 64; i++){
    if (tid < 192){
      int pbase = (i * (i - 1)) >> 1;
      float accv = 0.f;
      for (int j = 0; j < i; j++) accv += Pp[pbase + j] * X[j * 192 + tid];
      X[i * 192 + tid] -= accv;
    }
    __syncthreads();
  }

  // store Uv, W
  for (int e = tid; e < 12288; e += 256){
    int i = e / 192, colv = e - i * 192;
    float xv = X[e];
    if (colv < 128) Uvv[(size_t)blk * 8192 + i * 128 + colv] = xv;
    else            Wt [(size_t)blk * 4096 + i * 64 + (colv - 128)] = xv;
  }

  { // M = exp(G) I - K'^T W
    int d2 = tid & 63, d1b = tid >> 6;
    for (int ii = 0; ii < 16; ii++){
      int d1 = d1b * 16 + ii;
      float s = 0.f;
      for (int j = 0; j < 64; j++)
        s += eg[j] * Kc[j * 64 + d1] * X[j * 192 + 128 + d2];
      Mg[(size_t)blk * 4096 + d1 * 64 + d2] = ((d1 == d2) ? expf(GT) : 0.f) - s;
    }
  }
  { // N = K'^T Uv
    int vv = tid & 127, d1b = tid >> 7;
    for (int ii = 0; ii < 32; ii++){
      int d1 = d1b * 32 + ii;
      float s = 0.f;
      for (int j = 0; j < 64; j++)
        s += eg[j] * Kc[j * 64 + d1] * X[j * 192 + vv];
      Ng[(size_t)blk * 8192 + d1 * 128 + vv] = s;
    }
  }
  { // Cattn_ij = (q_i.k_j) exp(gt_i-gt_j), j <= i
    int i = tid >> 2, jb = tid & 3;
    float qi[64];
    {
      const float* src = qp + (size_t)(t0 + i) * 768 + h * 64;
      #pragma unroll
      for (int q4 = 0; q4 < 16; q4++){
        fx4 t4 = *(const fx4*)(src + q4 * 4);
        #pragma unroll
        for (int e = 0; e < 4; e++) qi[q4 * 4 + e] = t4[e];
      }
    }
    float gi = gt[i];
    for (int jj = 0; jj < 16; jj++){
      int j = jb * 16 + jj;
      float outv = 0.f;
      if (j <= i){
        float dot = 0.f;
        #pragma unroll
        for (int d = 0; d < 64; d++) dot += qi[d] * Kc[j * 64 + d];
        outv = dot * expf(gi - gt[j]);
      }
      Ca[(size_t)blk * 4096 + i * 64 + j] = outv;
    }
  }
  if (tid < 64) bv[(size_t)blk * 64 + tid] = bb[tid];
}

// ---------------------------------------------------------------- phase B: sequential S <- M S + N (per head)
__global__ __launch_bounds__(256)
void phaseB(const float* __restrict__ Mg, const float* __restrict__ Ng,
            float* __restrict__ Sst)
{
  const int h = blockIdx.x;
  const int tid = threadIdx.x, lane = tid & 63, w = tid >> 6;
  const int lm = lane & 15, lg = lane >> 4;
  __shared__ __align__(16) float ST[8192];   // S in [k-octet][v][8] layout

  #pragma unroll
  for (int e = 0; e < 8; e++)
    *(fx4*)&ST[(tid + e * 256) * 4] = (fx4){0.f,0.f,0.f,0.f};
  {
    float* dst = Sst + (size_t)h * 8192;     // S_states[0] = 0
    #pragma unroll
    for (int e = 0; e < 8; e++)
      *(fx4*)(dst + (size_t)(tid + e * 256) * 4) = (fx4){0.f,0.f,0.f,0.f};
  }
  __syncthreads();

  fx4 rm[2][2];
  float rn[8][4];
  auto loadMN = [&](int cc){
    const float* mb = Mg + ((size_t)cc * 12 + h) * 4096 + (w * 16 + lm) * 64 + lg * 8;
    rm[0][0] = *(const fx4*)(mb);
    rm[0][1] = *(const fx4*)(mb + 4);
    rm[1][0] = *(const fx4*)(mb + 32);
    rm[1][1] = *(const fx4*)(mb + 36);
    const float* nb = Ng + ((size_t)cc * 12 + h) * 8192;
    #pragma unroll
    for (int nt = 0; nt < 8; nt++)
      #pragma unroll
      for (int j = 0; j < 4; j++)
        rn[nt][j] = nb[(w * 16 + lg * 4 + j) * 128 + nt * 16 + lm];
  };
  loadMN(0);

  for (int c = 0; c < 32; c++){
    hx8 mf[2];
    #pragma unroll
    for (int s = 0; s < 2; s++)
      #pragma unroll
      for (int e = 0; e < 4; e++){
        mf[s][e]     = (_Float16)rm[s][0][e];
        mf[s][4 + e] = (_Float16)rm[s][1][e];
      }
    fx4 acc[8];
    #pragma unroll
    for (int nt = 0; nt < 8; nt++)
      #pragma unroll
      for (int j = 0; j < 4; j++) acc[nt][j] = rn[nt][j];
    if (c + 1 < 32) loadMN(c + 1);

    hx8 bfr[2][8];
    #pragma unroll
    for (int s = 0; s < 2; s++)
      #pragma unroll
      for (int nt = 0; nt < 8; nt++){
        int vv = nt * 16 + lm, kb = s * 4 + lg;
        fx4 p0 = *(const fx4*)&ST[kb * 1024 + vv * 8];
        fx4 p1 = *(const fx4*)&ST[kb * 1024 + vv * 8 + 4];
        #pragma unroll
        for (int e = 0; e < 4; e++){
          bfr[s][nt][e]     = (_Float16)p0[e];
          bfr[s][nt][4 + e] = (_Float16)p1[e];
        }
      }
    #pragma unroll
    for (int s = 0; s < 2; s++)
      #pragma unroll
      for (int nt = 0; nt < 8; nt++)
        acc[nt] = __builtin_amdgcn_mfma_f32_16x16x32_f16(mf[s], bfr[s][nt], acc[nt], 0, 0, 0);
    __syncthreads();   // all ST reads done
    float* dstS = (c + 1 < 32) ? (Sst + ((size_t)(c + 1) * 12 + h) * 8192) : nullptr;
    #pragma unroll
    for (int nt = 0; nt < 8; nt++){
      int vv = nt * 16 + lm;
      #pragma unroll
      for (int j = 0; j < 4; j++){
        int r = w * 16 + lg * 4 + j;
        ST[(r >> 3) * 1024 + vv * 8 + (r & 7)] = acc[nt][j];
        if (dstS) dstS[(size_t)r * 128 + vv] = acc[nt][j];
      }
    }
    __syncthreads();
  }
}

// ---------------------------------------------------------------- phase C: chunk outputs
__global__ __launch_bounds__(256)
void phaseC(const float* __restrict__ qp, const float* __restrict__ Sst,
            const float* __restrict__ Wt, const float* __restrict__ Uvv,
            const float* __restrict__ Ca, const float* __restrict__ bv,
            float* __restrict__ oraw)
{
  const int blk = blockIdx.x;
  const int h = blk % 12, c = blk / 12, t0 = c * 64;
  const int tid = threadIdx.x;

  __shared__ __align__(16) float S0l[8192];
  __shared__ __align__(16) float Ul[8192];
  __shared__ __align__(16) float Wl[4096];
  __shared__ __align__(16) float Ql[4096];
  __shared__ float bl[64];

  #pragma unroll
  for (int e = 0; e < 8; e++){
    int i4 = tid + e * 256;
    *(fx4*)&S0l[i4 * 4] = *(const fx4*)(Sst + (size_t)blk * 8192 + i4 * 4);
    *(fx4*)&Ul[i4 * 4]  = *(const fx4*)(Uvv + (size_t)blk * 8192 + i4 * 4);
  }
  #pragma unroll
  for (int e = 0; e < 4; e++){
    int i4 = tid + e * 256;
    *(fx4*)&Wl[i4 * 4] = *(const fx4*)(Wt + (size_t)blk * 4096 + i4 * 4);
  }
  {
    int i = tid >> 2, q4 = tid & 3;
    const float* src = qp + (size_t)(t0 + i) * 768 + h * 64 + q4 * 16;
    #pragma unroll
    for (int e = 0; e < 4; e++)
      *(fx4*)&Ql[i * 64 + q4 * 16 + e * 4] = *(const fx4*)(src + e * 4);
  }
  if (tid < 64) bl[tid] = bv[(size_t)blk * 64 + tid];
  __syncthreads();

  const int v = tid & 127, rh = tid >> 7;
  float s0c[64];
  #pragma unroll
  for (int d = 0; d < 64; d++) s0c[d] = S0l[d * 128 + v];

  // U = Uv - W @ S0
  for (int j = rh * 32; j < rh * 32 + 32; j++){
    float accv = 0.f;
    #pragma unroll
    for (int d = 0; d < 64; d++) accv += Wl[j * 64 + d] * s0c[d];
    Ul[j * 128 + v] -= accv;
  }
  __syncthreads();
  #pragma unroll
  for (int e = 0; e < 4; e++){   // Cattn into Wl
    int i4 = tid + e * 256;
    *(fx4*)&Wl[i4 * 4] = *(const fx4*)(Ca + (size_t)blk * 4096 + i4 * 4);
  }
  __syncthreads();

  // o_i = b_i * q_i S0 + sum_{j<=i} Cattn_ij U_j
  for (int i = rh * 32; i < rh * 32 + 32; i++){
    float aq = 0.f;
    #pragma unroll
    for (int d = 0; d < 64; d++) aq += Ql[i * 64 + d] * s0c[d];
    float ao = 0.f;
    for (int j = 0; j <= i; j++) ao += Wl[i * 64 + j] * Ul[j * 128 + v];
    oraw[(size_t)(t0 + i) * 1536 + h * 128 + v] = bl[i] * aq + ao;
  }
}

// ---------------------------------------------------------------- RMSNorm * g_norm_w * silu(g) -> fp16
__global__ __launch_bounds__(64)
void rmsgate(const float* __restrict__ oraw, const float* __restrict__ gx,
             const float* __restrict__ gnw, _Float16* __restrict__ ogh)
{
  int t = blockIdx.x, h = blockIdx.y, lane = threadIdx.x;
  size_t base = (size_t)t * 1536 + h * 128;
  float o1 = oraw[base + lane], o2 = oraw[base + 64 + lane];
  float ss = o1 * o1 + o2 * o2;
  #pragma unroll
  for (int d = 1; d < 64; d <<= 1) ss += __shfl_xor(ss, d, 64);
  float r = rsqrtf(ss * (1.f / 128.f) + 1e-5f);
  float g1 = gx[base + lane], g2 = gx[base + 64 + lane];
  ogh[base + lane]      = (_Float16)(o1 * r * gnw[lane]      * (g1 / (1.f + expf(-g1))));
  ogh[base + 64 + lane] = (_Float16)(o2 * r * gnw[64 + lane] * (g2 / (1.f + expf(-g2))));
}

// ---------------------------------------------------------------- launcher
extern "C" void kernel_launch(void* const* d_in, const int* in_sizes, int n_in,
                              void* d_out, int out_size, void* d_ws, size_t ws_size,
                              hipStream_t stream)
{
  const int*   ids   = (const int*)d_in[0];
  const float* emb   = (const float*)d_in[1];
  const float* Wq    = (const float*)d_in[2];
  const float* Wk    = (const float*)d_in[3];
  const float* Wv    = (const float*)d_in[4];
  const float* Wg    = (const float*)d_in[5];
  const float* wqc   = (const float*)d_in[6];
  const float* wkc   = (const float*)d_in[7];
  const float* wvc   = (const float*)d_in[8];
  const float* Wgk   = (const float*)d_in[9];
  const float* Wb    = (const float*)d_in[10];
  const float* b_b   = (const float*)d_in[11];
  const float* A_log = (const float*)d_in[12];
  const float* dtb   = (const float*)d_in[13];
  const float* gnw   = (const float*)d_in[14];
  const float* Wo    = (const float*)d_in[15];
  const float* Wlm   = (const float*)d_in[16];
  const float* b_lm  = (const float*)d_in[17];
  float* out = (float*)d_out;

  // d_out (102.9M floats) doubles as scratch: all intermediates die before
  // the final LM GEMM overwrites d_out (it reads only h_h in d_ws).
  float* x    = out;               // 2048x1024 fp32 (for gkbeta)
  float* qx   = out + 2097152;     // 2048x768
  float* kx   = out + 3670016;     // 2048x768
  float* vx   = out + 5242880;     // 2048x1536
  float* gx   = out + 8388608;     // 2048x1536 (kept until rmsgate)
  float* qpp  = out + 11534336;    // 2048x768
  float* kpp  = out + 13107200;    // 2048x768
  float* vpp  = out + 14680064;    // 2048x1536
  float* gkb  = out + 17825792;    // 2048x12
  float* bet  = out + 17850368;    // 2048x12
  float* Wt   = out + 17874944;    // 384x64x64
  float* Uvv  = out + 19447808;    // 384x64x128
  float* Mg   = out + 22593536;    // 384x64x64
  float* Ng   = out + 24166400;    // 384x64x128
  float* Ca   = out + 27312128;    // 384x64x64
  float* bvv  = out + 28884992;    // 384x64
  float* Sst  = out + 28909568;    // 384x64x128 (chunk-start states)
  float* oraw = out + 32055296;    // 2048x1536
  _Float16* x_h  = (_Float16*)(out + 35201024);  // 2048x1024 fp16
  _Float16* og_h = (_Float16*)(out + 36300000);  // 2048x1536 fp16
  _Float16* h_h  = (_Float16*)d_ws;              // 2048x1024 fp16 (survives LM GEMM)

  embed_k<<<2048, 256, 0, stream>>>(ids, emb, x, x_h);
  gemm16<false><<<dim3(16, 6),  256, 0, stream>>>(x_h, Wq, qx, nullptr, 2048, 768, 1024);
  gemm16<false><<<dim3(16, 6),  256, 0, stream>>>(x_h, Wk, kx, nullptr, 2048, 768, 1024);
  gemm16<false><<<dim3(16, 12), 256, 0, stream>>>(x_h, Wv, vx, nullptr, 2048, 1536, 1024);
  gemm16<false><<<dim3(16, 12), 256, 0, stream>>>(x_h, Wg, gx, nullptr, 2048, 1536, 1024);
  gkbeta_k<<<dim3(2048, 12), 64, 0, stream>>>(x, Wgk, Wb, b_b, A_log, dtb, gkb, bet);
  conv_silu<<<dim3(2048, 12), 64, 0, stream>>>(qx, wqc, qpp, 768, 1, 0.125f);
  conv_silu<<<dim3(2048, 12), 64, 0, stream>>>(kx, wkc, kpp, 768, 1, 1.0f);
  conv_silu<<<dim3(2048, 24), 64, 0, stream>>>(vx, wvc, vpp, 1536, 0, 1.0f);
  phaseA<<<384, 256, 0, stream>>>(qpp, kpp, vpp, gkb, bet, Wt, Uvv, Mg, Ng, Ca, bvv);
  phaseB<<<12, 256, 0, stream>>>(Mg, Ng, Sst);
  phaseC<<<384, 256, 0, stream>>>(qpp, Sst, Wt, Uvv, Ca, bvv, oraw);
  rmsgate<<<dim3(2048, 12), 64, 0, stream>>>(oraw, gx, gnw, og_h);
  gemm16<true><<<dim3(16, 8),   256, 0, stream>>>(og_h, Wo, h_h, nullptr, 2048, 1024, 1536);
  gemm16<false><<<dim3(16, 393), 256, 0, stream>>>(h_h, Wlm, out, b_lm, 2048, 50257, 1024);
}